// Round 8
// baseline (435.431 us; speedup 1.0000x reference)
//
#include <hip/hip_runtime.h>

#define NB 128
#define NT 512
#define NL 256
#define BG 16            // batches per workgroup
#define NWG (NB / BG)    // 8 workgroups

typedef float f32x4 __attribute__((ext_vector_type(4)));

#define EASTRIDE 272     // bytes per batch row of EA (256 + 16 pad)
#define PMSTRIDE 36      // floats per batch row of pm partials (32 + 4 pad)
#define GEXP 7           // a-priori per-step log2 growth estimate
#define INV_LN2 1.4426950408889634f
#define LN2 0.6931471805599453f

__device__ inline float log2_fast(float x) {
#if __has_builtin(__builtin_amdgcn_logf)
    return __builtin_amdgcn_logf(x);
#else
    return __log2f(x);
#endif
}
__device__ inline float exp2_fast(float x) {
#if __has_builtin(__builtin_amdgcn_exp2f)
    return __builtin_amdgcn_exp2f(x);
#else
    return exp2f(x);
#endif
}

// Barrier that waits only on LDS ops — prefetch global loads stay in flight.
__device__ inline void barrier_lds_only() {
    asm volatile("s_waitcnt lgkmcnt(0)" ::: "memory");
    __builtin_amdgcn_s_barrier();
    asm volatile("" ::: "memory");
}

// pack 4 f32 -> 4 fp8 e4m3 bytes (saturating)
__device__ inline unsigned pk_fp8x4(float a, float b, float c, float d) {
    int w = __builtin_amdgcn_cvt_pk_fp8_f32(a, b, 0, false);
    w     = __builtin_amdgcn_cvt_pk_fp8_f32(c, d, w, true);
    return (unsigned)w;
}

__device__ inline float4 max4(float4 a, float4 b) {
    return make_float4(fmaxf(a.x, b.x), fmaxf(a.y, b.y),
                       fmaxf(a.z, b.z), fmaxf(a.w, b.w));
}

// One WG (512 thr = 8 waves) per 16 batches.  Per step (ONE barrier, one LDS
// round-trip on the chain):
//   v[i,b]  = (sum_k expM[i,k]*EA[k,b]) * exp2(e_t[i,b]*INV_LN2 - kb)
//   kb      = floor(log2(STALE max_i EA[i,b])) + GEXP     (damped, 1-step lag)
//   EA_next = v (fp8, saturate 448);  S_b += kb
// Stability: E_t = log2 max(EA_t) obeys E_t = frac(E_{t-1}+G) + (g_t - G) —
// the floor re-centers each step, deviations never integrate (unlike a
// multiplicative scale chain).  The stale pm read, 31-op max tree, exponent
// extract and exp2(e/ln2 - kb) all hide under bfr ds_read + MFMA latency.
// Lane mapping (16x16x32, dtype-independent): b = l&15, g = l>>4;
// A: row=b, k=g*8+j; B: col=b, k=g*8+j; D: col=b, row=g*4+reg.
__global__ __launch_bounds__(512, 2) void crf_forward(
    const float* __restrict__ emis,
    const float* __restrict__ trans,
    const int*   __restrict__ words,
    float*       __restrict__ bout)
{
    const int tid = threadIdx.x;
    const int l   = tid & 63;
    const int wv  = tid >> 6;    // 0..7
    const int g   = l >> 4;      // 0..3
    const int b   = l & 15;

    __shared__ __align__(16) unsigned char ea[2][BG][EASTRIDE]; // fp8 EA, dbuf
    __shared__ __align__(16) float pm[2][BG][PMSTRIDE];         // stale maxes
    __shared__ float sump[BG][16];
    __shared__ float lzb[BG];

    const int wrow = (blockIdx.x * BG + b) * NT;

    // ---- A-fragments: exp(trans) rows owned by this wave, fp8 (32 VGPRs) ----
    long afr[2][8];
    #pragma unroll
    for (int T = 0; T < 2; ++T) {
        const int row = wv * 32 + T * 16 + b;
        #pragma unroll
        for (int kt = 0; kt < 8; ++kt) {
            const float* src = trans + row * NL + kt * 32 + g * 8;
            float4 v0 = *reinterpret_cast<const float4*>(src);
            float4 v1 = *reinterpret_cast<const float4*>(src + 4);
            unsigned u0 = pk_fp8x4(__expf(v0.x), __expf(v0.y), __expf(v0.z), __expf(v0.w));
            unsigned u1 = pk_fp8x4(__expf(v1.x), __expf(v1.y), __expf(v1.z), __expf(v1.w));
            afr[T][kt] = (long)(((unsigned long long)u1 << 32) | u0);
        }
    }

    // ---- pipelines: words 4 ahead, emissions 2 ahead ----
    const int w0 = words[wrow + 0];
    const int w1 = words[wrow + 1];
    const int w2 = words[wrow + 2];
    int wregA = words[wrow + 3];
    int wregB = words[wrow + 4];

    float S = 0.f;   // per-batch exponent accumulator (exact small ints)

    // ---- t=0 : EA_0 = fp8(2^(e0*INV_LN2))  (range ~2^±7, no norm needed) ----
    {
        const float* e0 = emis + (size_t)w0 * NL + wv * 32 + g * 4;
        float4 va = *reinterpret_cast<const float4*>(e0);
        float4 vb = *reinterpret_cast<const float4*>(e0 + 16);
        float v0[4] = { exp2_fast(va.x * INV_LN2), exp2_fast(va.y * INV_LN2),
                        exp2_fast(va.z * INV_LN2), exp2_fast(va.w * INV_LN2) };
        float v1[4] = { exp2_fast(vb.x * INV_LN2), exp2_fast(vb.y * INV_LN2),
                        exp2_fast(vb.z * INV_LN2), exp2_fast(vb.w * INV_LN2) };
        *reinterpret_cast<unsigned*>(&ea[0][b][wv * 32 + g * 4]) =
            pk_fp8x4(v0[0], v0[1], v0[2], v0[3]);
        *reinterpret_cast<unsigned*>(&ea[0][b][wv * 32 + 16 + g * 4]) =
            pk_fp8x4(v1[0], v1[1], v1[2], v1[3]);
        float pmax = fmaxf(fmaxf(fmaxf(v0[0], v0[1]), fmaxf(v0[2], v0[3])),
                           fmaxf(fmaxf(v1[0], v1[1]), fmaxf(v1[2], v1[3])));
        pm[0][b][wv * 4 + g] = pmax;
    }
    float4 pfA[2], pfB[2];
    {
        const float* p1 = emis + (size_t)w1 * NL + wv * 32 + g * 4;
        pfA[0] = *reinterpret_cast<const float4*>(p1);
        pfA[1] = *reinterpret_cast<const float4*>(p1 + 16);
        const float* p2 = emis + (size_t)w2 * NL + wv * 32 + g * 4;
        pfB[0] = *reinterpret_cast<const float4*>(p2);
        pfB[1] = *reinterpret_cast<const float4*>(p2 + 16);
    }
    barrier_lds_only();

#define CRF_STEP(t, RD, WR, PF, WREG)                                           \
    {                                                                           \
        /* issued together: bfr + stale pm (both LDS; latency shared) */        \
        long bfr[8];                                                            \
        _Pragma("unroll")                                                       \
        for (int kt = 0; kt < 8; ++kt)                                          \
            bfr[kt] = *reinterpret_cast<const long*>(&ea[RD][b][kt * 32 + g * 8]);\
        const float4* pmr = reinterpret_cast<const float4*>(&pm[RD][b][0]);     \
        float4 q0 = pmr[0], q1 = pmr[1], q2 = pmr[2], q3 = pmr[3];              \
        float4 q4 = pmr[4], q5 = pmr[5], q6 = pmr[6], q7 = pmr[7];              \
        float4 mA = max4(max4(q0, q1), max4(q2, q3));                           \
        float4 mB = max4(max4(q4, q5), max4(q6, q7));                           \
        float4 mm = max4(mA, mB);                                               \
        float gm  = fmaxf(fmaxf(mm.x, mm.y), fmaxf(mm.z, mm.w));                \
        int   kb  = (int)(__builtin_bit_cast(unsigned, gm) >> 23) - (127 - GEXP);\
        S += (float)kb;                                                         \
        float kbf = (float)kb;                                                  \
        float4 eC0 = PF[0], eC1 = PF[1];                                        \
        if ((t) + 2 < NT) {                                                     \
            const float* ep = emis + (size_t)WREG * NL + wv * 32 + g * 4;       \
            PF[0] = *reinterpret_cast<const float4*>(ep);                       \
            PF[1] = *reinterpret_cast<const float4*>(ep + 16);                  \
        }                                                                       \
        if ((t) + 4 < NT) WREG = words[wrow + (t) + 4];                         \
        /* scale folded into exp2 arg; hides under lgkm/MFMA wait */            \
        float ex0[4] = { exp2_fast(fmaf(eC0.x, INV_LN2, -kbf)),                 \
                         exp2_fast(fmaf(eC0.y, INV_LN2, -kbf)),                 \
                         exp2_fast(fmaf(eC0.z, INV_LN2, -kbf)),                 \
                         exp2_fast(fmaf(eC0.w, INV_LN2, -kbf)) };               \
        float ex1[4] = { exp2_fast(fmaf(eC1.x, INV_LN2, -kbf)),                 \
                         exp2_fast(fmaf(eC1.y, INV_LN2, -kbf)),                 \
                         exp2_fast(fmaf(eC1.z, INV_LN2, -kbf)),                 \
                         exp2_fast(fmaf(eC1.w, INV_LN2, -kbf)) };               \
        /* 8 independent depth-2 MFMA chains */                                 \
        f32x4 acc[2][4];                                                        \
        _Pragma("unroll")                                                       \
        for (int T = 0; T < 2; ++T) {                                           \
            _Pragma("unroll")                                                   \
            for (int j = 0; j < 4; ++j) {                                       \
                f32x4 z = {0.f, 0.f, 0.f, 0.f};                                 \
                z = __builtin_amdgcn_mfma_f32_16x16x32_fp8_fp8(                 \
                        afr[T][j], bfr[j], z, 0, 0, 0);                         \
                acc[T][j] = __builtin_amdgcn_mfma_f32_16x16x32_fp8_fp8(         \
                        afr[T][j + 4], bfr[j + 4], z, 0, 0, 0);                 \
            }                                                                   \
        }                                                                       \
        f32x4 s0 = (acc[0][0] + acc[0][1]) + (acc[0][2] + acc[0][3]);           \
        f32x4 s1 = (acc[1][0] + acc[1][1]) + (acc[1][2] + acc[1][3]);           \
        float w0_ = s0[0] * ex0[0], w1_ = s0[1] * ex0[1];                       \
        float w2_ = s0[2] * ex0[2], w3_ = s0[3] * ex0[3];                       \
        float w4_ = s1[0] * ex1[0], w5_ = s1[1] * ex1[1];                       \
        float w6_ = s1[2] * ex1[2], w7_ = s1[3] * ex1[3];                       \
        *reinterpret_cast<unsigned*>(&ea[WR][b][wv * 32 + g * 4]) =             \
            pk_fp8x4(w0_, w1_, w2_, w3_);                                       \
        *reinterpret_cast<unsigned*>(&ea[WR][b][wv * 32 + 16 + g * 4]) =        \
            pk_fp8x4(w4_, w5_, w6_, w7_);                                       \
        float pmax = fmaxf(fmaxf(fmaxf(w0_, w1_), fmaxf(w2_, w3_)),             \
                           fmaxf(fmaxf(w4_, w5_), fmaxf(w6_, w7_)));            \
        pm[WR][b][wv * 4 + g] = pmax;                                           \
        barrier_lds_only();                                                     \
    }

    for (int t = 1; t < NT; t += 2) {
        CRF_STEP(t, 0, 1, pfA, wregA);
        if (t + 1 < NT) CRF_STEP(t + 1, 1, 0, pfB, wregB);
    }
#undef CRF_STEP

    // ---- final (last step t=511 wrote buffer 1):
    //      logZ_b = ln2 * (S_b + log2(sum_i EA_last[i,b])) ----
    if (tid < 256) {
        const int part = tid & 15;
        const int bb   = tid >> 4;
        const unsigned* p = reinterpret_cast<const unsigned*>(&ea[1][bb][part * 16]);
        float s = 0.f;
        #pragma unroll
        for (int w = 0; w < 4; ++w) {
            unsigned u = p[w];
            s += __builtin_amdgcn_cvt_f32_fp8((int)u, 0);
            s += __builtin_amdgcn_cvt_f32_fp8((int)u, 1);
            s += __builtin_amdgcn_cvt_f32_fp8((int)u, 2);
            s += __builtin_amdgcn_cvt_f32_fp8((int)u, 3);
        }
        sump[bb][part] = s;
    }
    __syncthreads();
    if (tid < BG) {
        float tot = 0.f;
        #pragma unroll
        for (int p = 0; p < 16; ++p) tot += sump[tid][p];
        // threads 0..15 have b == tid, so their S is batch tid's exponent sum
        lzb[tid] = (S + log2_fast(tot)) * LN2;
    }
    __syncthreads();
    if (tid == 0) {
        float p = 0.f;
        #pragma unroll
        for (int j = 0; j < BG; ++j) p += lzb[j];
        bout[blockIdx.x] = p;
    }
}

__global__ void crf_reduce(const float* __restrict__ bout, float* __restrict__ out)
{
    if (threadIdx.x == 0) {
        float s = 0.f;
        for (int j = 0; j < NWG; ++j) s += bout[j];
        out[0] = s;
    }
}

extern "C" void kernel_launch(void* const* d_in, const int* in_sizes, int n_in,
                              void* d_out, int out_size, void* d_ws, size_t ws_size,
                              hipStream_t stream)
{
    const float* emis  = (const float*)d_in[0];
    const float* trans = (const float*)d_in[1];
    const int*   words = (const int*)d_in[2];
    float* out  = (float*)d_out;
    float* bout = (float*)d_ws;   // NWG floats of scratch

    crf_forward<<<NWG, 512, 0, stream>>>(emis, trans, words, bout);
    crf_reduce<<<1, 64, 0, stream>>>(bout, out);
}

// Round 9
// 391.243 us; speedup vs baseline: 1.1129x; 1.1129x over previous
//
#include <hip/hip_runtime.h>

#define NB 128
#define NT 512
#define NL 256
#define BG 2             // batches per workgroup (gather-spread: 2 KB/CU-step)
#define NWG (NB / BG)    // 64 workgroups

typedef float f32x4 __attribute__((ext_vector_type(4)));

#define EASTRIDE 272     // bytes per batch row of EA (256 + 16 pad)
#define PMSTRIDE 36      // floats per batch row of pm partials (32 + 4 pad)
#define GEXP 7           // a-priori per-step log2 growth estimate
#define INV_LN2 1.4426950408889634f
#define LN2 0.6931471805599453f

__device__ inline float log2_fast(float x) {
#if __has_builtin(__builtin_amdgcn_logf)
    return __builtin_amdgcn_logf(x);
#else
    return __log2f(x);
#endif
}
__device__ inline float exp2_fast(float x) {
#if __has_builtin(__builtin_amdgcn_exp2f)
    return __builtin_amdgcn_exp2f(x);
#else
    return exp2f(x);
#endif
}

// Barrier that waits only on LDS ops — prefetch global loads stay in flight.
__device__ inline void barrier_lds_only() {
    asm volatile("s_waitcnt lgkmcnt(0)" ::: "memory");
    __builtin_amdgcn_s_barrier();
    asm volatile("" ::: "memory");
}

// pack 4 f32 -> 4 fp8 e4m3 bytes (saturating)
__device__ inline unsigned pk_fp8x4(float a, float b, float c, float d) {
    int w = __builtin_amdgcn_cvt_pk_fp8_f32(a, b, 0, false);
    w     = __builtin_amdgcn_cvt_pk_fp8_f32(c, d, w, true);
    return (unsigned)w;
}

__device__ inline float4 max4(float4 a, float4 b) {
    return make_float4(fmaxf(a.x, b.x), fmaxf(a.y, b.y),
                       fmaxf(a.z, b.z), fmaxf(a.w, b.w));
}

// One WG (512 thr = 8 waves) per BG=2 batches.  Identical numerics to round 8
// (absmax 0.0): exp-space recurrence, damped power-of-2 normalization with a
// one-step-stale max, S accumulates exact integer exponents.  Only change:
// BG 16 -> 2 so the per-CU emission-gather drops 16 KB -> 2 KB per step
// (the r5-r8 invariant floor was per-CU VMEM return BW ~10 B/cy).
// Lanes with b >= BG duplicate lane b&1's data (reads aliased, writes guarded).
__global__ __launch_bounds__(512, 2) void crf_forward(
    const float* __restrict__ emis,
    const float* __restrict__ trans,
    const int*   __restrict__ words,
    float*       __restrict__ bout)
{
    const int tid = threadIdx.x;
    const int l   = tid & 63;
    const int wv  = tid >> 6;    // 0..7
    const int g   = l >> 4;      // 0..3
    const int b   = l & 15;
    const int bb  = b & (BG - 1);   // effective batch lane

    __shared__ __align__(16) unsigned char ea[2][BG][EASTRIDE]; // fp8 EA, dbuf
    __shared__ __align__(16) float pm[2][BG][PMSTRIDE];         // stale maxes
    __shared__ float sump[BG][16];
    __shared__ float lzb[BG];

    const int wrow = (blockIdx.x * BG + bb) * NT;

    // ---- A-fragments: exp(trans) rows owned by this wave, fp8 (32 VGPRs) ----
    long afr[2][8];
    #pragma unroll
    for (int T = 0; T < 2; ++T) {
        const int row = wv * 32 + T * 16 + b;
        #pragma unroll
        for (int kt = 0; kt < 8; ++kt) {
            const float* src = trans + row * NL + kt * 32 + g * 8;
            float4 v0 = *reinterpret_cast<const float4*>(src);
            float4 v1 = *reinterpret_cast<const float4*>(src + 4);
            unsigned u0 = pk_fp8x4(__expf(v0.x), __expf(v0.y), __expf(v0.z), __expf(v0.w));
            unsigned u1 = pk_fp8x4(__expf(v1.x), __expf(v1.y), __expf(v1.z), __expf(v1.w));
            afr[T][kt] = (long)(((unsigned long long)u1 << 32) | u0);
        }
    }

    // ---- pipelines: words 4 ahead, emissions 2 ahead ----
    const int w0 = words[wrow + 0];
    const int w1 = words[wrow + 1];
    const int w2 = words[wrow + 2];
    int wregA = words[wrow + 3];
    int wregB = words[wrow + 4];

    float S = 0.f;   // per-batch exponent accumulator (exact small ints)

    // ---- t=0 : EA_0 = fp8(2^(e0*INV_LN2))  (range ~2^±7, no norm needed) ----
    {
        const float* e0 = emis + (size_t)w0 * NL + wv * 32 + g * 4;
        float4 va = *reinterpret_cast<const float4*>(e0);
        float4 vb = *reinterpret_cast<const float4*>(e0 + 16);
        float v0[4] = { exp2_fast(va.x * INV_LN2), exp2_fast(va.y * INV_LN2),
                        exp2_fast(va.z * INV_LN2), exp2_fast(va.w * INV_LN2) };
        float v1[4] = { exp2_fast(vb.x * INV_LN2), exp2_fast(vb.y * INV_LN2),
                        exp2_fast(vb.z * INV_LN2), exp2_fast(vb.w * INV_LN2) };
        float pmax = fmaxf(fmaxf(fmaxf(v0[0], v0[1]), fmaxf(v0[2], v0[3])),
                           fmaxf(fmaxf(v1[0], v1[1]), fmaxf(v1[2], v1[3])));
        if (b < BG) {
            *reinterpret_cast<unsigned*>(&ea[0][b][wv * 32 + g * 4]) =
                pk_fp8x4(v0[0], v0[1], v0[2], v0[3]);
            *reinterpret_cast<unsigned*>(&ea[0][b][wv * 32 + 16 + g * 4]) =
                pk_fp8x4(v1[0], v1[1], v1[2], v1[3]);
            pm[0][b][wv * 4 + g] = pmax;
        }
    }
    float4 pfA[2], pfB[2];
    {
        const float* p1 = emis + (size_t)w1 * NL + wv * 32 + g * 4;
        pfA[0] = *reinterpret_cast<const float4*>(p1);
        pfA[1] = *reinterpret_cast<const float4*>(p1 + 16);
        const float* p2 = emis + (size_t)w2 * NL + wv * 32 + g * 4;
        pfB[0] = *reinterpret_cast<const float4*>(p2);
        pfB[1] = *reinterpret_cast<const float4*>(p2 + 16);
    }
    barrier_lds_only();

#define CRF_STEP(t, RD, WR, PF, WREG)                                           \
    {                                                                           \
        /* issued together: bfr + stale pm (both LDS; latency shared) */        \
        long bfr[8];                                                            \
        _Pragma("unroll")                                                       \
        for (int kt = 0; kt < 8; ++kt)                                          \
            bfr[kt] = *reinterpret_cast<const long*>(&ea[RD][bb][kt * 32 + g * 8]);\
        const float4* pmr = reinterpret_cast<const float4*>(&pm[RD][bb][0]);    \
        float4 q0 = pmr[0], q1 = pmr[1], q2 = pmr[2], q3 = pmr[3];              \
        float4 q4 = pmr[4], q5 = pmr[5], q6 = pmr[6], q7 = pmr[7];              \
        float4 mA = max4(max4(q0, q1), max4(q2, q3));                           \
        float4 mB = max4(max4(q4, q5), max4(q6, q7));                           \
        float4 mm = max4(mA, mB);                                               \
        float gm  = fmaxf(fmaxf(mm.x, mm.y), fmaxf(mm.z, mm.w));                \
        int   kb  = (int)(__builtin_bit_cast(unsigned, gm) >> 23) - (127 - GEXP);\
        S += (float)kb;                                                         \
        float kbf = (float)kb;                                                  \
        float4 eC0 = PF[0], eC1 = PF[1];                                        \
        if ((t) + 2 < NT) {                                                     \
            const float* ep = emis + (size_t)WREG * NL + wv * 32 + g * 4;       \
            PF[0] = *reinterpret_cast<const float4*>(ep);                       \
            PF[1] = *reinterpret_cast<const float4*>(ep + 16);                  \
        }                                                                       \
        if ((t) + 4 < NT) WREG = words[wrow + (t) + 4];                         \
        /* scale folded into exp2 arg; hides under lgkm/MFMA wait */            \
        float ex0[4] = { exp2_fast(fmaf(eC0.x, INV_LN2, -kbf)),                 \
                         exp2_fast(fmaf(eC0.y, INV_LN2, -kbf)),                 \
                         exp2_fast(fmaf(eC0.z, INV_LN2, -kbf)),                 \
                         exp2_fast(fmaf(eC0.w, INV_LN2, -kbf)) };               \
        float ex1[4] = { exp2_fast(fmaf(eC1.x, INV_LN2, -kbf)),                 \
                         exp2_fast(fmaf(eC1.y, INV_LN2, -kbf)),                 \
                         exp2_fast(fmaf(eC1.z, INV_LN2, -kbf)),                 \
                         exp2_fast(fmaf(eC1.w, INV_LN2, -kbf)) };               \
        /* 8 independent depth-2 MFMA chains */                                 \
        f32x4 acc[2][4];                                                        \
        _Pragma("unroll")                                                       \
        for (int T = 0; T < 2; ++T) {                                           \
            _Pragma("unroll")                                                   \
            for (int j = 0; j < 4; ++j) {                                       \
                f32x4 z = {0.f, 0.f, 0.f, 0.f};                                 \
                z = __builtin_amdgcn_mfma_f32_16x16x32_fp8_fp8(                 \
                        afr[T][j], bfr[j], z, 0, 0, 0);                         \
                acc[T][j] = __builtin_amdgcn_mfma_f32_16x16x32_fp8_fp8(         \
                        afr[T][j + 4], bfr[j + 4], z, 0, 0, 0);                 \
            }                                                                   \
        }                                                                       \
        f32x4 s0 = (acc[0][0] + acc[0][1]) + (acc[0][2] + acc[0][3]);           \
        f32x4 s1 = (acc[1][0] + acc[1][1]) + (acc[1][2] + acc[1][3]);           \
        float w0_ = s0[0] * ex0[0], w1_ = s0[1] * ex0[1];                       \
        float w2_ = s0[2] * ex0[2], w3_ = s0[3] * ex0[3];                       \
        float w4_ = s1[0] * ex1[0], w5_ = s1[1] * ex1[1];                       \
        float w6_ = s1[2] * ex1[2], w7_ = s1[3] * ex1[3];                       \
        float pmax = fmaxf(fmaxf(fmaxf(w0_, w1_), fmaxf(w2_, w3_)),             \
                           fmaxf(fmaxf(w4_, w5_), fmaxf(w6_, w7_)));            \
        if (b < BG) {                                                           \
            *reinterpret_cast<unsigned*>(&ea[WR][b][wv * 32 + g * 4]) =         \
                pk_fp8x4(w0_, w1_, w2_, w3_);                                   \
            *reinterpret_cast<unsigned*>(&ea[WR][b][wv * 32 + 16 + g * 4]) =    \
                pk_fp8x4(w4_, w5_, w6_, w7_);                                   \
            pm[WR][b][wv * 4 + g] = pmax;                                       \
        }                                                                       \
        barrier_lds_only();                                                     \
    }

    for (int t = 1; t < NT; t += 2) {
        CRF_STEP(t, 0, 1, pfA, wregA);
        if (t + 1 < NT) CRF_STEP(t + 1, 1, 0, pfB, wregB);
    }
#undef CRF_STEP

    // ---- final (last step t=511 wrote buffer 1):
    //      logZ_b = ln2 * (S_b + log2(sum_i EA_last[i,b])) ----
    if (tid < 16 * BG) {
        const int part = tid & 15;
        const int bq   = tid >> 4;   // < BG
        const unsigned* p = reinterpret_cast<const unsigned*>(&ea[1][bq][part * 16]);
        float s = 0.f;
        #pragma unroll
        for (int w = 0; w < 4; ++w) {
            unsigned u = p[w];
            s += __builtin_amdgcn_cvt_f32_fp8((int)u, 0);
            s += __builtin_amdgcn_cvt_f32_fp8((int)u, 1);
            s += __builtin_amdgcn_cvt_f32_fp8((int)u, 2);
            s += __builtin_amdgcn_cvt_f32_fp8((int)u, 3);
        }
        sump[bq][part] = s;
    }
    __syncthreads();
    if (tid < BG) {
        float tot = 0.f;
        #pragma unroll
        for (int p = 0; p < 16; ++p) tot += sump[tid][p];
        // threads 0..BG-1 have bb == tid, so their S is batch tid's exponent sum
        lzb[tid] = (S + log2_fast(tot)) * LN2;
    }
    __syncthreads();
    if (tid == 0) {
        float p = 0.f;
        #pragma unroll
        for (int j = 0; j < BG; ++j) p += lzb[j];
        bout[blockIdx.x] = p;
    }
}

__global__ void crf_reduce(const float* __restrict__ bout, float* __restrict__ out)
{
    const int tid = threadIdx.x;  // 64 threads
    float v = bout[tid];
    #pragma unroll
    for (int off = 32; off; off >>= 1) v += __shfl_xor(v, off);
    if (tid == 0) out[0] = v;
}

extern "C" void kernel_launch(void* const* d_in, const int* in_sizes, int n_in,
                              void* d_out, int out_size, void* d_ws, size_t ws_size,
                              hipStream_t stream)
{
    const float* emis  = (const float*)d_in[0];
    const float* trans = (const float*)d_in[1];
    const int*   words = (const int*)d_in[2];
    float* out  = (float*)d_out;
    float* bout = (float*)d_ws;   // NWG floats of scratch

    crf_forward<<<NWG, 512, 0, stream>>>(emis, trans, words, bout);
    crf_reduce<<<1, NWG, 0, stream>>>(bout, out);
}

// Round 10
// 378.364 us; speedup vs baseline: 1.1508x; 1.0340x over previous
//
#include <hip/hip_runtime.h>

#define NB 128
#define NT 512
#define NL 256
#define NWG NB           // one workgroup per batch

typedef float f32x4 __attribute__((ext_vector_type(4)));
typedef long  lx2   __attribute__((ext_vector_type(2)));

#define EASTRIDE 272     // bytes per EA buffer (256 + 16 pad, 16B aligned)
#define GEXP 7           // a-priori per-step log2 growth estimate
#define INV_LN2 1.4426950408889634f
#define LN2 0.6931471805599453f

__device__ inline float log2_fast(float x) {
#if __has_builtin(__builtin_amdgcn_logf)
    return __builtin_amdgcn_logf(x);
#else
    return __log2f(x);
#endif
}
__device__ inline float exp2_fast(float x) {
#if __has_builtin(__builtin_amdgcn_exp2f)
    return __builtin_amdgcn_exp2f(x);
#else
    return exp2f(x);
#endif
}

// Barrier that waits only on LDS ops — prefetch global loads stay in flight.
__device__ inline void barrier_lds_only() {
    asm volatile("s_waitcnt lgkmcnt(0)" ::: "memory");
    __builtin_amdgcn_s_barrier();
    asm volatile("" ::: "memory");
}

// pack 4 f32 -> 4 fp8 e4m3 bytes (saturating)
__device__ inline unsigned pk_fp8x4(float a, float b, float c, float d) {
    int w = __builtin_amdgcn_cvt_pk_fp8_f32(a, b, 0, false);
    w     = __builtin_amdgcn_cvt_pk_fp8_f32(c, d, w, true);
    return (unsigned)w;
}

// One WG (256 thr = 4 waves) per batch.  Numerics identical to r8/r9
// (absmax 0.0): exp-space recurrence, damped power-of-2 normalization from a
// one-step-stale max, S accumulates exact integer exponents.
// DS-pipe minimization (the r5-r9 invariant floor):
//  * EA stored PERMUTED: addr(k) = ((k>>3)&3)*64 + (k>>5)*8 + (k&7)
//    -> each lane-group's 8 B-frags are 64 contiguous bytes = 4 ds_read_b128
//    (broadcast across the 16 column lanes).
//  * pm = 4 floats (one per wave, in-wave shuffle-max first) = 1 ds_read_b128.
//  * column lanes are batch-duplicates -> lane b writes i-tile T=b:
//    EA write = 1 ds_write_b32 per wave.
// Per CU-step DS ~= 4 waves x (4x b128 + 1x b128 + 2 shfl + 2x b32) ~ 340 cy.
__global__ __launch_bounds__(256, 1) void crf_forward(
    const float* __restrict__ emis,
    const float* __restrict__ trans,
    const int*   __restrict__ words,
    float*       __restrict__ bout)
{
    const int tid = threadIdx.x;
    const int l   = tid & 63;
    const int wv  = tid >> 6;    // 0..3
    const int g   = l >> 4;      // 0..3
    const int b   = l & 15;

    __shared__ __align__(16) unsigned char ea[2][EASTRIDE]; // fp8 EA, permuted, dbuf
    __shared__ __align__(16) float pm[2][4];                // per-wave stale maxes

    const int wrow = blockIdx.x * NT;

    // ---- A-fragments: exp(trans), rows row = wv*64 + T*16 + b (64 VGPRs) ----
    long afr[4][8];
    #pragma unroll
    for (int T = 0; T < 4; ++T) {
        const int row = wv * 64 + T * 16 + b;
        #pragma unroll
        for (int kt = 0; kt < 8; ++kt) {
            const float* src = trans + row * NL + kt * 32 + g * 8;
            float4 v0 = *reinterpret_cast<const float4*>(src);
            float4 v1 = *reinterpret_cast<const float4*>(src + 4);
            unsigned u0 = pk_fp8x4(__expf(v0.x), __expf(v0.y), __expf(v0.z), __expf(v0.w));
            unsigned u1 = pk_fp8x4(__expf(v1.x), __expf(v1.y), __expf(v1.z), __expf(v1.w));
            afr[T][kt] = (long)(((unsigned long long)u1 << 32) | u0);
        }
    }

    // ---- pipelines: emissions 4 deep, word indices 8 ahead (uniform/SGPR) ----
    const int w0 = words[wrow + 0];
    const int w1 = words[wrow + 1];
    const int w2 = words[wrow + 2];
    const int w3 = words[wrow + 3];
    const int w4 = words[wrow + 4];
    int wregA = words[wrow + 5];
    int wregB = words[wrow + 6];
    int wregC = words[wrow + 7];
    int wregD = words[wrow + 8];

    float S = 0.f;   // exponent accumulator (exact small ints, same in all lanes)

    // ---- t=0 : EA_0 = fp8(2^(e0*INV_LN2)), rows wv*64 + T*16 + g*4 + j ----
    {
        const float* e0 = emis + (size_t)w0 * NL + wv * 64 + g * 4;
        f32x4 v[4];
        #pragma unroll
        for (int T = 0; T < 4; ++T) v[T] = *reinterpret_cast<const f32x4*>(e0 + T * 16);
        f32x4 p2[4];
        float pmax = 0.f;
        unsigned pk[4];
        #pragma unroll
        for (int T = 0; T < 4; ++T) {
            p2[T][0] = exp2_fast(v[T][0] * INV_LN2);
            p2[T][1] = exp2_fast(v[T][1] * INV_LN2);
            p2[T][2] = exp2_fast(v[T][2] * INV_LN2);
            p2[T][3] = exp2_fast(v[T][3] * INV_LN2);
            pmax = fmaxf(pmax, fmaxf(fmaxf(p2[T][0], p2[T][1]),
                                     fmaxf(p2[T][2], p2[T][3])));
            pk[T] = pk_fp8x4(p2[T][0], p2[T][1], p2[T][2], p2[T][3]);
        }
        pmax = fmaxf(pmax, __shfl_xor(pmax, 16));
        pmax = fmaxf(pmax, __shfl_xor(pmax, 32));
        if (l == 0) pm[0][wv] = pmax;
        if (b < 4) {  // lane b writes i-tile T=b
            const int T  = b;
            const int gr = (T * 2 + (g >> 1)) & 3;
            const int kt = wv * 2 + (T >> 1);
            const int j0 = (g & 1) * 4;
            unsigned val = (b == 0) ? pk[0] : (b == 1) ? pk[1] : (b == 2) ? pk[2] : pk[3];
            *reinterpret_cast<unsigned*>(&ea[0][gr * 64 + kt * 8 + j0]) = val;
        }
    }
    f32x4 pfA[4], pfB[4], pfC[4], pfD[4];
    {
        const float* p;
        p = emis + (size_t)w1 * NL + wv * 64 + g * 4;
        pfA[0] = *(const f32x4*)p; pfA[1] = *(const f32x4*)(p + 16);
        pfA[2] = *(const f32x4*)(p + 32); pfA[3] = *(const f32x4*)(p + 48);
        p = emis + (size_t)w2 * NL + wv * 64 + g * 4;
        pfB[0] = *(const f32x4*)p; pfB[1] = *(const f32x4*)(p + 16);
        pfB[2] = *(const f32x4*)(p + 32); pfB[3] = *(const f32x4*)(p + 48);
        p = emis + (size_t)w3 * NL + wv * 64 + g * 4;
        pfC[0] = *(const f32x4*)p; pfC[1] = *(const f32x4*)(p + 16);
        pfC[2] = *(const f32x4*)(p + 32); pfC[3] = *(const f32x4*)(p + 48);
        p = emis + (size_t)w4 * NL + wv * 64 + g * 4;
        pfD[0] = *(const f32x4*)p; pfD[1] = *(const f32x4*)(p + 16);
        pfD[2] = *(const f32x4*)(p + 32); pfD[3] = *(const f32x4*)(p + 48);
    }
    barrier_lds_only();

#define CRF_STEP(t, RD, WR, PF, WREG)                                           \
    {                                                                           \
        /* bfr: 4 contiguous b128 reads (broadcast within lane-group) */        \
        lx2 q0 = *reinterpret_cast<const lx2*>(&ea[RD][g * 64 +  0]);           \
        lx2 q1 = *reinterpret_cast<const lx2*>(&ea[RD][g * 64 + 16]);           \
        lx2 q2 = *reinterpret_cast<const lx2*>(&ea[RD][g * 64 + 32]);           \
        lx2 q3 = *reinterpret_cast<const lx2*>(&ea[RD][g * 64 + 48]);           \
        f32x4 pmv = *reinterpret_cast<const f32x4*>(&pm[RD][0]);                \
        float gm  = fmaxf(fmaxf(pmv[0], pmv[1]), fmaxf(pmv[2], pmv[3]));        \
        int   kb  = (int)(__builtin_bit_cast(unsigned, gm) >> 23) - (127 - GEXP);\
        S += (float)kb;                                                         \
        float kbf = (float)kb;                                                  \
        f32x4 eC[4] = { PF[0], PF[1], PF[2], PF[3] };                           \
        if ((t) + 4 < NT) {                                                     \
            const float* ep = emis + (size_t)WREG * NL + wv * 64 + g * 4;       \
            PF[0] = *(const f32x4*)ep;        PF[1] = *(const f32x4*)(ep + 16); \
            PF[2] = *(const f32x4*)(ep + 32); PF[3] = *(const f32x4*)(ep + 48); \
        }                                                                       \
        if ((t) + 8 < NT) WREG = words[wrow + (t) + 8];                         \
        /* ex hides under lgkm/MFMA wait */                                     \
        f32x4 ex[4];                                                            \
        _Pragma("unroll")                                                       \
        for (int T = 0; T < 4; ++T) {                                           \
            ex[T][0] = exp2_fast(fmaf(eC[T][0], INV_LN2, -kbf));                \
            ex[T][1] = exp2_fast(fmaf(eC[T][1], INV_LN2, -kbf));                \
            ex[T][2] = exp2_fast(fmaf(eC[T][2], INV_LN2, -kbf));                \
            ex[T][3] = exp2_fast(fmaf(eC[T][3], INV_LN2, -kbf));                \
        }                                                                       \
        /* per i-tile: two independent depth-4 MFMA chains */                   \
        f32x4 sA[4];                                                            \
        _Pragma("unroll")                                                       \
        for (int T = 0; T < 4; ++T) {                                           \
            f32x4 z0 = {0.f, 0.f, 0.f, 0.f};                                    \
            f32x4 z1 = {0.f, 0.f, 0.f, 0.f};                                    \
            z0 = __builtin_amdgcn_mfma_f32_16x16x32_fp8_fp8(afr[T][0], q0[0], z0, 0, 0, 0); \
            z1 = __builtin_amdgcn_mfma_f32_16x16x32_fp8_fp8(afr[T][4], q2[0], z1, 0, 0, 0); \
            z0 = __builtin_amdgcn_mfma_f32_16x16x32_fp8_fp8(afr[T][1], q0[1], z0, 0, 0, 0); \
            z1 = __builtin_amdgcn_mfma_f32_16x16x32_fp8_fp8(afr[T][5], q2[1], z1, 0, 0, 0); \
            z0 = __builtin_amdgcn_mfma_f32_16x16x32_fp8_fp8(afr[T][2], q1[0], z0, 0, 0, 0); \
            z1 = __builtin_amdgcn_mfma_f32_16x16x32_fp8_fp8(afr[T][6], q3[0], z1, 0, 0, 0); \
            z0 = __builtin_amdgcn_mfma_f32_16x16x32_fp8_fp8(afr[T][3], q1[1], z0, 0, 0, 0); \
            z1 = __builtin_amdgcn_mfma_f32_16x16x32_fp8_fp8(afr[T][7], q3[1], z1, 0, 0, 0); \
            sA[T] = z0 + z1;                                                    \
        }                                                                       \
        float pmax = 0.f;                                                       \
        unsigned pk[4];                                                         \
        _Pragma("unroll")                                                       \
        for (int T = 0; T < 4; ++T) {                                           \
            f32x4 wv4 = sA[T] * ex[T];                                          \
            pmax = fmaxf(pmax, fmaxf(fmaxf(wv4[0], wv4[1]),                     \
                                     fmaxf(wv4[2], wv4[3])));                   \
            pk[T] = pk_fp8x4(wv4[0], wv4[1], wv4[2], wv4[3]);                   \
        }                                                                       \
        pmax = fmaxf(pmax, __shfl_xor(pmax, 16));                               \
        pmax = fmaxf(pmax, __shfl_xor(pmax, 32));                               \
        if (l == 0) pm[WR][wv] = pmax;                                          \
        if (b < 4) {                                                            \
            const int T  = b;                                                   \
            const int gr = (T * 2 + (g >> 1)) & 3;                              \
            const int kt = wv * 2 + (T >> 1);                                   \
            const int j0 = (g & 1) * 4;                                         \
            unsigned val = (b == 0) ? pk[0] : (b == 1) ? pk[1]                  \
                         : (b == 2) ? pk[2] : pk[3];                            \
            *reinterpret_cast<unsigned*>(&ea[WR][gr * 64 + kt * 8 + j0]) = val; \
        }                                                                       \
        barrier_lds_only();                                                     \
    }

    int t = 1;
    for (; t + 3 < NT; t += 4) {
        CRF_STEP(t,     0, 1, pfA, wregA);
        CRF_STEP(t + 1, 1, 0, pfB, wregB);
        CRF_STEP(t + 2, 0, 1, pfC, wregC);
        CRF_STEP(t + 3, 1, 0, pfD, wregD);
    }
    // tail: t = 509, 510, 511  (parity: WR = t&1; final EA lands in ea[1])
    CRF_STEP(509, 0, 1, pfA, wregA);
    CRF_STEP(510, 1, 0, pfB, wregB);
    CRF_STEP(511, 0, 1, pfC, wregC);
#undef CRF_STEP

    // ---- final: logZ_b = ln2 * (S + log2(sum_k EA_last[k]))  (perm-invariant sum)
    if (tid < 64) {
        unsigned u = *reinterpret_cast<const unsigned*>(&ea[1][tid * 4]);
        float s = __builtin_amdgcn_cvt_f32_fp8((int)u, 0)
                + __builtin_amdgcn_cvt_f32_fp8((int)u, 1)
                + __builtin_amdgcn_cvt_f32_fp8((int)u, 2)
                + __builtin_amdgcn_cvt_f32_fp8((int)u, 3);
        #pragma unroll
        for (int off = 32; off; off >>= 1) s += __shfl_xor(s, off);
        if (tid == 0) bout[blockIdx.x] = (S + log2_fast(s)) * LN2;
    }
}

__global__ void crf_reduce(const float* __restrict__ bout, float* __restrict__ out)
{
    const int tid = threadIdx.x;  // 128 threads
    float v = bout[tid];
    #pragma unroll
    for (int off = 32; off; off >>= 1) v += __shfl_xor(v, off);
    __shared__ float sred[2];
    if ((tid & 63) == 0) sred[tid >> 6] = v;
    __syncthreads();
    if (tid == 0) out[0] = sred[0] + sred[1];
}

extern "C" void kernel_launch(void* const* d_in, const int* in_sizes, int n_in,
                              void* d_out, int out_size, void* d_ws, size_t ws_size,
                              hipStream_t stream)
{
    const float* emis  = (const float*)d_in[0];
    const float* trans = (const float*)d_in[1];
    const int*   words = (const int*)d_in[2];
    float* out  = (float*)d_out;
    float* bout = (float*)d_ws;   // NWG floats of scratch

    crf_forward<<<NWG, 256, 0, stream>>>(emis, trans, words, bout);
    crf_reduce<<<1, NB, 0, stream>>>(bout, out);
}

// Round 11
// 306.010 us; speedup vs baseline: 1.4229x; 1.2364x over previous
//
#include <hip/hip_runtime.h>

#define NB 128
#define NT 512
#define NL 256
#define NWG NB           // one workgroup per batch

typedef float f32x4 __attribute__((ext_vector_type(4)));
typedef int   i32x8 __attribute__((ext_vector_type(8)));
typedef int   i32x4v __attribute__((ext_vector_type(4)));

#define EASTRIDE 272     // bytes per EA buffer (256 + 16 pad, 16B aligned)
#define GEXP 7           // a-priori per-step log2 growth estimate
#define E8M0_ONE 127     // e8m0 encoding of 1.0 for mfma_scale
#define INV_LN2 1.4426950408889634f
#define LN2 0.6931471805599453f

__device__ inline float log2_fast(float x) {
#if __has_builtin(__builtin_amdgcn_logf)
    return __builtin_amdgcn_logf(x);
#else
    return __log2f(x);
#endif
}
__device__ inline float exp2_fast(float x) {
#if __has_builtin(__builtin_amdgcn_exp2f)
    return __builtin_amdgcn_exp2f(x);
#else
    return exp2f(x);
#endif
}

// Barrier that waits only on LDS ops — prefetch global loads stay in flight.
__device__ inline void barrier_lds_only() {
    asm volatile("s_waitcnt lgkmcnt(0)" ::: "memory");
    __builtin_amdgcn_s_barrier();
    asm volatile("" ::: "memory");
}

// pack 4 f32 -> 4 fp8 e4m3 bytes (saturating)
__device__ inline unsigned pk_fp8x4(float a, float b, float c, float d) {
    int w = __builtin_amdgcn_cvt_pk_fp8_f32(a, b, 0, false);
    w     = __builtin_amdgcn_cvt_pk_fp8_f32(c, d, w, true);
    return (unsigned)w;
}

// 32 contiguous LDS bytes -> v8i32 (two b128 reads)
__device__ inline i32x8 ld_b256(const unsigned char* p) {
    i32x4v lo = *reinterpret_cast<const i32x4v*>(p);
    i32x4v hi = *reinterpret_cast<const i32x4v*>(p + 16);
    i32x8 r;
    r[0] = lo[0]; r[1] = lo[1]; r[2] = lo[2]; r[3] = lo[3];
    r[4] = hi[0]; r[5] = hi[1]; r[6] = hi[2]; r[7] = hi[3];
    return r;
}

// One WG (256 thr = 4 waves) per batch.  Numerics identical to r8-r10
// (absmax 0.0): exp-space recurrence, damped power-of-2 normalization from a
// one-step-stale max, S accumulates exact integer exponents.
// Issue-model fixes (r10 post-mortem: MFMA 620 cy/SIMD at K=32 was the top
// issue-term; uniform s_load of words drained by every lgkmcnt(0) barrier):
//  * mfma_scale_f32_16x16x128_f8f6f4 (unit scales): 32 -> 8 MFMA per wave,
//    ~277 cy/SIMD.  B-frag: lane (g,b) reads ea[kt*128+g*32 .. +31] — natural
//    contiguous layout, 2x ds_read_b128 broadcast per kt, no permutation.
//  * words staged to LDS once; per-step refresh is ds_read_b32 (cheap drain).
// Layout (16x16x128, shape-determined): A row=lane&15, k=(lane>>4)*32+j;
// B col=lane&15 (batch dup), k=(lane>>4)*32+j; D col=lane&15, row=g*4+reg.
__global__ __launch_bounds__(256, 1) void crf_forward(
    const float* __restrict__ emis,
    const float* __restrict__ trans,
    const int*   __restrict__ words,
    float*       __restrict__ bout)
{
    const int tid = threadIdx.x;
    const int l   = tid & 63;
    const int wv  = tid >> 6;    // 0..3
    const int g   = l >> 4;      // 0..3
    const int b   = l & 15;

    __shared__ __align__(16) unsigned char ea[2][EASTRIDE]; // fp8 EA, dbuf
    __shared__ __align__(16) float pm[2][4];                // per-wave stale maxes
    __shared__ int wlds[NT];                                // staged word indices

    const int wrow = blockIdx.x * NT;

    // ---- stage word indices to LDS (uniform s_loads only in prologue) ----
    wlds[tid]       = words[wrow + tid];
    wlds[tid + 256] = words[wrow + tid + 256];

    // ---- A-fragments: exp(trans) rows wv*64 + T*16 + b, K=128 layout ----
    // afr[T][kt] = 32 fp8 bytes = exp(trans[row][kt*128 + g*32 .. +31])
    i32x8 afr[4][2];
    #pragma unroll
    for (int T = 0; T < 4; ++T) {
        const int row = wv * 64 + T * 16 + b;
        #pragma unroll
        for (int kt = 0; kt < 2; ++kt) {
            const float* src = trans + row * NL + kt * 128 + g * 32;
            i32x8 a;
            #pragma unroll
            for (int w = 0; w < 8; ++w) {
                float4 v = *reinterpret_cast<const float4*>(src + w * 4);
                a[w] = (int)pk_fp8x4(__expf(v.x), __expf(v.y),
                                     __expf(v.z), __expf(v.w));
            }
            afr[T][kt] = a;
        }
    }

    // ---- word pipeline (prologue: direct reads; steady: wlds ds_read) ----
    const int w0 = words[wrow + 0];
    const int w1 = words[wrow + 1];
    const int w2 = words[wrow + 2];
    const int w3 = words[wrow + 3];
    const int w4 = words[wrow + 4];
    int wregA = words[wrow + 5];
    int wregB = words[wrow + 6];
    int wregC = words[wrow + 7];
    int wregD = words[wrow + 8];

    float S = 0.f;   // exponent accumulator (exact small ints, same in all lanes)

    // ---- t=0 : EA_0 = fp8(2^(e0*INV_LN2)), rows wv*64 + T*16 + g*4 + j ----
    {
        const float* e0 = emis + (size_t)w0 * NL + wv * 64 + g * 4;
        float pmax = 0.f;
        unsigned pk[4];
        #pragma unroll
        for (int T = 0; T < 4; ++T) {
            f32x4 v = *reinterpret_cast<const f32x4*>(e0 + T * 16);
            float p0 = exp2_fast(v[0] * INV_LN2);
            float p1 = exp2_fast(v[1] * INV_LN2);
            float p2 = exp2_fast(v[2] * INV_LN2);
            float p3 = exp2_fast(v[3] * INV_LN2);
            pmax = fmaxf(pmax, fmaxf(fmaxf(p0, p1), fmaxf(p2, p3)));
            pk[T] = pk_fp8x4(p0, p1, p2, p3);
        }
        pmax = fmaxf(pmax, __shfl_xor(pmax, 16));
        pmax = fmaxf(pmax, __shfl_xor(pmax, 32));
        if (l == 0) pm[0][wv] = pmax;
        if (b == 0) {
            #pragma unroll
            for (int T = 0; T < 4; ++T)
                *reinterpret_cast<unsigned*>(&ea[0][wv * 64 + T * 16 + g * 4]) = pk[T];
        }
    }
    f32x4 pfA[4], pfB[4], pfC[4], pfD[4];
    {
        const float* p;
        p = emis + (size_t)w1 * NL + wv * 64 + g * 4;
        pfA[0] = *(const f32x4*)p; pfA[1] = *(const f32x4*)(p + 16);
        pfA[2] = *(const f32x4*)(p + 32); pfA[3] = *(const f32x4*)(p + 48);
        p = emis + (size_t)w2 * NL + wv * 64 + g * 4;
        pfB[0] = *(const f32x4*)p; pfB[1] = *(const f32x4*)(p + 16);
        pfB[2] = *(const f32x4*)(p + 32); pfB[3] = *(const f32x4*)(p + 48);
        p = emis + (size_t)w3 * NL + wv * 64 + g * 4;
        pfC[0] = *(const f32x4*)p; pfC[1] = *(const f32x4*)(p + 16);
        pfC[2] = *(const f32x4*)(p + 32); pfC[3] = *(const f32x4*)(p + 48);
        p = emis + (size_t)w4 * NL + wv * 64 + g * 4;
        pfD[0] = *(const f32x4*)p; pfD[1] = *(const f32x4*)(p + 16);
        pfD[2] = *(const f32x4*)(p + 32); pfD[3] = *(const f32x4*)(p + 48);
    }
    barrier_lds_only();

#define CRF_STEP(t, RD, WR, PF, WREG)                                           \
    {                                                                           \
        /* B-frags: natural contiguous, broadcast b128 reads */                 \
        i32x8 bq0 = ld_b256(&ea[RD][g * 32]);                                   \
        i32x8 bq1 = ld_b256(&ea[RD][128 + g * 32]);                             \
        f32x4 pmv = *reinterpret_cast<const f32x4*>(&pm[RD][0]);                \
        float gm  = fmaxf(fmaxf(pmv[0], pmv[1]), fmaxf(pmv[2], pmv[3]));        \
        int   kb  = (int)(__builtin_bit_cast(unsigned, gm) >> 23) - (127 - GEXP);\
        S += (float)kb;                                                         \
        float kbf = (float)kb;                                                  \
        f32x4 eC[4] = { PF[0], PF[1], PF[2], PF[3] };                           \
        if ((t) + 4 < NT) {                                                     \
            const float* ep = emis + (size_t)WREG * NL + wv * 64 + g * 4;       \
            PF[0] = *(const f32x4*)ep;        PF[1] = *(const f32x4*)(ep + 16); \
            PF[2] = *(const f32x4*)(ep + 32); PF[3] = *(const f32x4*)(ep + 48); \
        }                                                                       \
        if ((t) + 8 < NT) WREG = wlds[(t) + 8];                                 \
        /* ex hides under lgkm/MFMA wait */                                     \
        f32x4 ex[4];                                                            \
        _Pragma("unroll")                                                       \
        for (int T = 0; T < 4; ++T) {                                           \
            ex[T][0] = exp2_fast(fmaf(eC[T][0], INV_LN2, -kbf));                \
            ex[T][1] = exp2_fast(fmaf(eC[T][1], INV_LN2, -kbf));                \
            ex[T][2] = exp2_fast(fmaf(eC[T][2], INV_LN2, -kbf));                \
            ex[T][3] = exp2_fast(fmaf(eC[T][3], INV_LN2, -kbf));                \
        }                                                                       \
        /* 4 independent depth-2 scale-MFMA chains (K=128 each) */              \
        f32x4 sA[4];                                                            \
        _Pragma("unroll")                                                       \
        for (int T = 0; T < 4; ++T) {                                           \
            f32x4 z = {0.f, 0.f, 0.f, 0.f};                                     \
            z = __builtin_amdgcn_mfma_scale_f32_16x16x128_f8f6f4(               \
                    afr[T][0], bq0, z, 0, 0, 0, E8M0_ONE, 0, E8M0_ONE);         \
            z = __builtin_amdgcn_mfma_scale_f32_16x16x128_f8f6f4(               \
                    afr[T][1], bq1, z, 0, 0, 0, E8M0_ONE, 0, E8M0_ONE);         \
            sA[T] = z;                                                          \
        }                                                                       \
        float pmax = 0.f;                                                       \
        unsigned pk[4];                                                         \
        _Pragma("unroll")                                                       \
        for (int T = 0; T < 4; ++T) {                                           \
            f32x4 wv4 = sA[T] * ex[T];                                          \
            pmax = fmaxf(pmax, fmaxf(fmaxf(wv4[0], wv4[1]),                     \
                                     fmaxf(wv4[2], wv4[3])));                   \
            pk[T] = pk_fp8x4(wv4[0], wv4[1], wv4[2], wv4[3]);                   \
        }                                                                       \
        pmax = fmaxf(pmax, __shfl_xor(pmax, 16));                               \
        pmax = fmaxf(pmax, __shfl_xor(pmax, 32));                               \
        if (l == 0) pm[WR][wv] = pmax;                                          \
        if (b == 0) {                                                           \
            _Pragma("unroll")                                                   \
            for (int T = 0; T < 4; ++T)                                         \
                *reinterpret_cast<unsigned*>(                                   \
                    &ea[WR][wv * 64 + T * 16 + g * 4]) = pk[T];                 \
        }                                                                       \
        barrier_lds_only();                                                     \
    }

    int t = 1;
    for (; t + 3 < NT; t += 4) {
        CRF_STEP(t,     0, 1, pfA, wregA);
        CRF_STEP(t + 1, 1, 0, pfB, wregB);
        CRF_STEP(t + 2, 0, 1, pfC, wregC);
        CRF_STEP(t + 3, 1, 0, pfD, wregD);
    }
    // tail: t = 509, 510, 511  (parity: WR = t&1; final EA lands in ea[1])
    CRF_STEP(509, 0, 1, pfA, wregA);
    CRF_STEP(510, 1, 0, pfB, wregB);
    CRF_STEP(511, 0, 1, pfC, wregC);
#undef CRF_STEP

    // ---- final: logZ_b = ln2 * (S + log2(sum_k EA_last[k])) ----
    if (tid < 64) {
        unsigned u = *reinterpret_cast<const unsigned*>(&ea[1][tid * 4]);
        float s = __builtin_amdgcn_cvt_f32_fp8((int)u, 0)
                + __builtin_amdgcn_cvt_f32_fp8((int)u, 1)
                + __builtin_amdgcn_cvt_f32_fp8((int)u, 2)
                + __builtin_amdgcn_cvt_f32_fp8((int)u, 3);
        #pragma unroll
        for (int off = 32; off; off >>= 1) s += __shfl_xor(s, off);
        if (tid == 0) bout[blockIdx.x] = (S + log2_fast(s)) * LN2;
    }
}

__global__ void crf_reduce(const float* __restrict__ bout, float* __restrict__ out)
{
    const int tid = threadIdx.x;  // 128 threads
    float v = bout[tid];
    #pragma unroll
    for (int off = 32; off; off >>= 1) v += __shfl_xor(v, off);
    __shared__ float sred[2];
    if ((tid & 63) == 0) sred[tid >> 6] = v;
    __syncthreads();
    if (tid == 0) out[0] = sred[0] + sred[1];
}

extern "C" void kernel_launch(void* const* d_in, const int* in_sizes, int n_in,
                              void* d_out, int out_size, void* d_ws, size_t ws_size,
                              hipStream_t stream)
{
    const float* emis  = (const float*)d_in[0];
    const float* trans = (const float*)d_in[1];
    const int*   words = (const int*)d_in[2];
    float* out  = (float*)d_out;
    float* bout = (float*)d_ws;   // NWG floats of scratch

    crf_forward<<<NWG, 256, 0, stream>>>(emis, trans, words, bout);
    crf_reduce<<<1, NB, 0, stream>>>(bout, out);
}